// Round 4
// baseline (566.476 us; speedup 1.0000x reference)
//
#include <hip/hip_runtime.h>
#include <hip/hip_fp16.h>

// CapsNet dynamic routing, B=256, P=2048, C=10, OUT=16, IN=8, 3 iters.
// K1 (k_uhat v2): b*p tiled (64p x 32b per block), LDS-free. Thread holds 8
//   u-rows in regs (8x W reuse), streams W from global (L1/L2-hot), writes
//   dense 16B chunks into per-b regions. R3's block=p scattered 256 regions
//   655KB apart -> 1.3 TB/s write; this fills 40KB regions densely.
// K2 (k_route v2): TPB 1024 (16 waves/CU; R3 had 8 -> latency-starved at
//   VALUBusy 15%). Lane pairs split c-space, acc[5][16]=80 VGPR, no spill.

#define Bn 256
#define Pn 2048
#define Cn 10
#define On 16
#define In 8
#define ROW 160            // Cn*On
#define TPB 1024
#define PAIRS (TPB / 2)    // 512
#define ITERS (Pn / PAIRS) // 4
#define NW (TPB / 64)      // 16 waves
#define CH 5               // c's per half-thread
#define HROW 80            // CH*On

typedef _Float16 h2f __attribute__((ext_vector_type(2)));

// ---------------- k_uhat ----------------
// grid = 256: blockIdx = bt*32 + pt  (pt in [0,32), bt in [0,8))
// same-pt blocks are stride-32 apart == same XCD (x%8) -> W chunk L2-resident.
__global__ __launch_bounds__(256) void k_uhat(const float* __restrict__ u,
                                              const float* __restrict__ W,
                                              __half* __restrict__ uhat) {
  const int t = threadIdx.x;
  const int pt = blockIdx.x & 31;
  const int bt = blockIdx.x >> 5;
  const int p_loc = t >> 2;   // [0,64): wave covers 16 consecutive p
  const int b_grp = t & 3;    // 4 groups of 8 b
  const int p = pt * 64 + p_loc;
  const int b0 = bt * 32 + b_grp * 8;

  float ur[8][8];
#pragma unroll
  for (int bb = 0; bb < 8; ++bb) {
    const float4* up =
        reinterpret_cast<const float4*>(u + ((size_t)(b0 + bb) * Pn + p) * In);
    float4 x0 = up[0], x1 = up[1];
    ur[bb][0] = x0.x; ur[bb][1] = x0.y; ur[bb][2] = x0.z; ur[bb][3] = x0.w;
    ur[bb][4] = x1.x; ur[bb][5] = x1.y; ur[bb][6] = x1.z; ur[bb][7] = x1.w;
  }
  const float* wr = W + (size_t)p * (Cn * On * In); // p*1280
  __half* obase = uhat + (size_t)p * ROW;

  for (int ch = 0; ch < 20; ++ch) { // 8 (c,o)-cells per chunk = 16B fp16
    union { float4 f; __half2 h2[4]; } ov[8];
#pragma unroll
    for (int jp = 0; jp < 4; ++jp) {
      const int co0 = ch * 8 + jp * 2;
      float4 wa = *reinterpret_cast<const float4*>(wr + co0 * 8);
      float4 wb = *reinterpret_cast<const float4*>(wr + co0 * 8 + 4);
      float4 wc = *reinterpret_cast<const float4*>(wr + co0 * 8 + 8);
      float4 wd = *reinterpret_cast<const float4*>(wr + co0 * 8 + 12);
#pragma unroll
      for (int bb = 0; bb < 8; ++bb) {
        float d0 = wa.x * ur[bb][0];
        d0 = __builtin_fmaf(wa.y, ur[bb][1], d0);
        d0 = __builtin_fmaf(wa.z, ur[bb][2], d0);
        d0 = __builtin_fmaf(wa.w, ur[bb][3], d0);
        d0 = __builtin_fmaf(wb.x, ur[bb][4], d0);
        d0 = __builtin_fmaf(wb.y, ur[bb][5], d0);
        d0 = __builtin_fmaf(wb.z, ur[bb][6], d0);
        d0 = __builtin_fmaf(wb.w, ur[bb][7], d0);
        float d1 = wc.x * ur[bb][0];
        d1 = __builtin_fmaf(wc.y, ur[bb][1], d1);
        d1 = __builtin_fmaf(wc.z, ur[bb][2], d1);
        d1 = __builtin_fmaf(wc.w, ur[bb][3], d1);
        d1 = __builtin_fmaf(wd.x, ur[bb][4], d1);
        d1 = __builtin_fmaf(wd.y, ur[bb][5], d1);
        d1 = __builtin_fmaf(wd.z, ur[bb][6], d1);
        d1 = __builtin_fmaf(wd.w, ur[bb][7], d1);
        ov[bb].h2[jp] = __floats2half2_rn(d0, d1);
      }
    }
#pragma unroll
    for (int bb = 0; bb < 8; ++bb)
      *reinterpret_cast<float4*>(obase + (size_t)(b0 + bb) * Pn * ROW + ch * 8) =
          ov[bb].f;
  }
}

// ---------------- k_route ----------------
__device__ __forceinline__ void reduce_squash(float (&acc)[CH][On], float scale,
                                              int tid, int lane, int w, int h,
                                              float (*s_red)[ROW], float* s_lds,
                                              float* v_lds, __half2 (*v_h2)[8]) {
#pragma unroll
  for (int k = 0; k < HROW; ++k) {
    float x = acc[k >> 4][k & 15];
#pragma unroll
    for (int off = 2; off <= 32; off <<= 1) x += __shfl_xor(x, off, 64);
    if ((lane >> 1) == (k & 31)) s_red[w][h * HROW + k] = x;
  }
  __syncthreads();
  if (tid < ROW) {
    float tsum = 0.f;
#pragma unroll
    for (int ww = 0; ww < NW; ++ww) tsum += s_red[ww][tid];
    s_lds[tid] = scale * tsum;
  }
  __syncthreads();
  if (tid < Cn) {
    float sq = 0.f;
#pragma unroll
    for (int o = 0; o < On; ++o) {
      float x = s_lds[tid * On + o];
      sq += x * x;
    }
    float sc = (sq / (1.f + sq)) / sqrtf(sq + 1e-9f);
#pragma unroll
    for (int o = 0; o < On; ++o) v_lds[tid * On + o] = sc * s_lds[tid * On + o];
#pragma unroll
    for (int o2 = 0; o2 < 8; ++o2)
      v_h2[tid][o2] = __floats2half2_rn(v_lds[tid * On + 2 * o2],
                                        v_lds[tid * On + 2 * o2 + 1]);
  }
  __syncthreads();
}

__global__ __launch_bounds__(TPB) void k_route(const __half* __restrict__ uhat,
                                               float* __restrict__ out) {
  __shared__ __half lg_lds[Pn][2][CH]; // 40960 B
  __shared__ float s_red[NW][ROW];     // 10240 B
  __shared__ float s_lds[ROW];
  __shared__ float v_lds[ROW];
  __shared__ __half2 v_h2[Cn][8];
  const int b = blockIdx.x;
  const int tid = threadIdx.x;
  const int lane = tid & 63;
  const int w = tid >> 6;
  const int h = tid & 1;   // c-half this thread owns
  const int pr = tid >> 1; // pair index in [0,512)
  const __half* base = uhat + (size_t)b * Pn * ROW + h * HROW;

  float acc[CH][On];

  // ---- PASS 1: weights uniform 0.1 ----
#pragma unroll
  for (int kc = 0; kc < CH; ++kc)
#pragma unroll
    for (int o = 0; o < On; ++o) acc[kc][o] = 0.f;
  for (int it = 0; it < ITERS; ++it) {
    const __half* row = base + (size_t)(pr + PAIRS * it) * ROW;
#pragma unroll
    for (int kc = 0; kc < CH; ++kc) {
      union { float4 f[2]; __half hh[16]; } q;
      q.f[0] = *reinterpret_cast<const float4*>(row + kc * 16);
      q.f[1] = *reinterpret_cast<const float4*>(row + kc * 16 + 8);
#pragma unroll
      for (int o = 0; o < On; ++o) acc[kc][o] += __half2float(q.hh[o]);
    }
  }
  reduce_squash(acc, 0.1f, tid, lane, w, h, s_red, s_lds, v_lds, v_h2);

  // ---- PASSES 2,3 (b-update folded into softmax) ----
  for (int pass = 0; pass < 2; ++pass) {
#pragma unroll
    for (int kc = 0; kc < CH; ++kc)
#pragma unroll
      for (int o = 0; o < On; ++o) acc[kc][o] = 0.f;
    for (int it = 0; it < ITERS; ++it) {
      const int p = pr + PAIRS * it;
      const __half* row = base + (size_t)p * ROW;
      float lg[CH];
#pragma unroll
      for (int kc = 0; kc < CH; ++kc) {
        union { float4 f[2]; h2f hh2[8]; } q;
        q.f[0] = *reinterpret_cast<const float4*>(row + kc * 16);
        q.f[1] = *reinterpret_cast<const float4*>(row + kc * 16 + 8);
        float d = 0.f;
#pragma unroll
        for (int o2 = 0; o2 < 8; ++o2) {
          h2f vv = *reinterpret_cast<const h2f*>(&v_h2[h * CH + kc][o2]); // uniform: LDS broadcast
          d = __builtin_amdgcn_fdot2(q.hh2[o2], vv, d, false);
        }
        lg[kc] = (pass == 0) ? d : (d + __half2float(lg_lds[p][h][kc]));
      }
      if (pass == 0) {
#pragma unroll
        for (int kc = 0; kc < CH; ++kc) lg_lds[p][h][kc] = __float2half(lg[kc]);
      }
      // softmax across both halves via 2 shuffles
      float m = lg[0];
#pragma unroll
      for (int kc = 1; kc < CH; ++kc) m = fmaxf(m, lg[kc]);
      m = fmaxf(m, __shfl_xor(m, 1, 64));
      float e[CH], ssum = 0.f;
#pragma unroll
      for (int kc = 0; kc < CH; ++kc) {
        e[kc] = __expf(lg[kc] - m);
        ssum += e[kc];
      }
      ssum += __shfl_xor(ssum, 1, 64);
      const float inv = 1.f / ssum;
#pragma unroll
      for (int kc = 0; kc < CH; ++kc) {
        union { float4 f[2]; __half hh[16]; } q;
        q.f[0] = *reinterpret_cast<const float4*>(row + kc * 16); // L1-hot reload
        q.f[1] = *reinterpret_cast<const float4*>(row + kc * 16 + 8);
        const float cv = e[kc] * inv;
#pragma unroll
        for (int o = 0; o < On; ++o)
          acc[kc][o] = __builtin_fmaf(cv, __half2float(q.hh[o]), acc[kc][o]);
      }
    }
    reduce_squash(acc, 1.0f, tid, lane, w, h, s_red, s_lds, v_lds, v_h2);
  }

  if (tid < ROW) out[(size_t)b * ROW + tid] = v_lds[tid];
}

extern "C" void kernel_launch(void* const* d_in, const int* in_sizes, int n_in,
                              void* d_out, int out_size, void* d_ws, size_t ws_size,
                              hipStream_t stream) {
  (void)in_sizes; (void)n_in; (void)out_size;
  const float* u = (const float*)d_in[0];
  const float* W = (const float*)d_in[1];
  float* out = (float*)d_out;
  __half* uhat = (__half*)d_ws;
  const size_t need = (size_t)Bn * Pn * Cn * On * sizeof(__half);
  if (ws_size < need) return; // needs ~168 MB scratch
  k_uhat<<<256, 256, 0, stream>>>(u, W, uhat);
  k_route<<<Bn, TPB, 0, stream>>>(uhat, out);
}